// Round 13
// baseline (266.458 us; speedup 1.0000x reference)
//
#include <hip/hip_runtime.h>
#include <stdint.h>

#define S_LEN   2048
#define HID_DIM 2880
#define NHEAD   64
#define NKVH    8
#define DHEAD   64
#define NQ      4096      // H*D
#define NKVD    512       // HKV*D
#define NQKV    5120      // NQ + 2*NKVD
#define WOPAD   2944      // 2880 padded to 23*128
#define ATT_SCALE 0.125f
#define NEGINF  (-1e30f)

typedef __attribute__((ext_vector_type(8))) short bf16x8;
typedef __attribute__((ext_vector_type(4))) float f32x4;

typedef __attribute__((address_space(3))) uint32_t lds_u32;
typedef const __attribute__((address_space(1))) uint32_t glb_u32;

// async global->LDS, 16B per lane. LDS dest semantics: wave-uniform base +
// lane*16 (per-lane l must be contiguous in lane order). Global src IS per-lane.
__device__ __forceinline__ void gl_lds16(const short* g, short* l) {
  __builtin_amdgcn_global_load_lds((glb_u32*)(uintptr_t)g,
                                   (lds_u32*)(uint32_t)(uintptr_t)l, 16, 0, 0);
}

__device__ __forceinline__ short f2bf(float f) {
  union { float f; uint32_t u; } c; c.f = f;
  uint32_t u = c.u;
  return (short)((u + 0x7FFFu + ((u >> 16) & 1u)) >> 16);  // RNE
}

// ---------------- fused prep: cvt x + 4 transpose-converts, one launch ----------------
// 1D grid, 256 threads. Regions (block ranges):
//   [0,5760)        cvt_x: 5760*256 float4 = 2048*2880 f32 -> bf16
//   [5760,17280)    Wq  [2880][4096] -> wqkvb[0..4096)[2880]      (90 x 128 tiles)
//   [17280,18720)   Wk  [2880][512]  -> wqkvb[4096..4608)[2880]   (90 x 16)
//   [18720,20160)   Wv  [2880][512]  -> wqkvb[4608..5120)[2880]   (90 x 16)
//   [20160,31936)   Wo  [4096][2880] -> wob[0..2944)[4096]        (128 x 92, pad rows zeroed)
__global__ __launch_bounds__(256) void k_prep(
    const float* __restrict__ x, short* __restrict__ xb,
    const float* __restrict__ Wq, const float* __restrict__ Wk,
    const float* __restrict__ Wv, const float* __restrict__ Wo,
    short* __restrict__ wqkvb, short* __restrict__ wob) {
  int b = blockIdx.x;
  if (b < 5760) {
    int i = b * 256 + threadIdx.x;
    float4 v = ((const float4*)x)[i];
    short4 o;
    o.x = f2bf(v.x); o.y = f2bf(v.y); o.z = f2bf(v.z); o.w = f2bf(v.w);
    ((short4*)xb)[i] = o;
    return;
  }
  b -= 5760;
  const float* src; short* dst; int K, N, tk;
  if (b < 11520) {
    src = Wq; dst = wqkvb; K = 2880; N = 4096; tk = 90;
  } else if (b < 11520 + 1440) {
    b -= 11520;
    src = Wk; dst = wqkvb + (size_t)NQ * HID_DIM; K = 2880; N = 512; tk = 90;
  } else if (b < 11520 + 2880) {
    b -= 11520 + 1440;
    src = Wv; dst = wqkvb + (size_t)(NQ + NKVD) * HID_DIM; K = 2880; N = 512; tk = 90;
  } else {
    b -= 11520 + 2880;
    src = Wo; dst = wob; K = 4096; N = 2880; tk = 128;
  }
  int k0 = (b % tk) * 32, n0 = (b / tk) * 32;
  __shared__ float tile[32][33];
  int tx = threadIdx.x & 31, ty = threadIdx.x >> 5;
#pragma unroll
  for (int j = 0; j < 4; ++j) {
    int n = n0 + tx, k = k0 + ty + j * 8;
    tile[ty + j * 8][tx] = (n < N) ? src[(size_t)k * N + n] : 0.f;
  }
  __syncthreads();
#pragma unroll
  for (int j = 0; j < 4; ++j) {
    int n = n0 + ty + j * 8;
    dst[(size_t)n * K + k0 + tx] = f2bf(tile[tx][ty + j * 8]);
  }
}

// ---------------- GEMM core: C[M x N] = A[M x K] * B[N x K]^T ----------------
// A bf16 row-major [M][K], B bf16 row-major [N][K]. 128x256 tile, BK=64,
// 512 threads = 8 waves (2x4), each wave 64x64 via 4x4 of 16x16x32 MFMA.
// Tile widened 128x128 -> 128x256 per the staged-bytes model (R12: GEMM time
// tracks total global_load_lds bytes at ~9-11 TB/s; (1/BM+1/BN) drops 25%).
// Single 48KB LDS buffer, 2-barrier loop (dbuf regressed twice, R6/R8).
// Swizzle: LDS linear, XOR (slot^(m&7)) on per-lane GLOBAL src and the same
// involution on ds_read -> conflict-free b128 both ways.
// EPI 0: bias + RoPE + split bf16 stores (q/k/v). EPI 1: bias + f32 store,
//        B-row reads clamped to WOPAD-1 (zeroed pad row) for the last tile,
//        stores guarded at n<2880.
template <int EPI>
__global__ __launch_bounds__(512) void k_gemm(
    const short* __restrict__ A, const short* __restrict__ B, int K,
    const float* __restrict__ biasq, const float* __restrict__ biask,
    const float* __restrict__ biasv,
    const float* __restrict__ cosT, const float* __restrict__ sinT,
    short* __restrict__ qout, short* __restrict__ kout, short* __restrict__ vout,
    const float* __restrict__ bo, float* __restrict__ out) {
  const int tid = threadIdx.x;
  const int lane = tid & 63, wid = tid >> 6;
  const int wm = wid >> 2, wn = wid & 3;     // 2 x 4 wave grid, wave = 64x64
  const int l15 = lane & 15, lhi = lane >> 4;
  const int row0 = blockIdx.y * 128, col0 = blockIdx.x * 256;

  __shared__ short As[128 * 64];   // 16KB
  __shared__ short Bs[256 * 64];   // 32KB

  f32x4 acc[4][4];
#pragma unroll
  for (int i = 0; i < 4; ++i)
#pragma unroll
    for (int j = 0; j < 4; ++j) acc[i][j] = (f32x4){0.f, 0.f, 0.f, 0.f};

  // staging coords: A = 1024 16B-chunks (2/thread), B = 2048 (4/thread);
  // global source slot is the swizzled ss = slot ^ (m&7).
  const short* aSrc[2];
  const short* bSrc[4];
  int aOff[2], bOff[4];
#pragma unroll
  for (int i = 0; i < 2; ++i) {
    int p = i * 512 + tid;
    int m = p >> 3, slot = p & 7;
    int ss = slot ^ (m & 7);
    aSrc[i] = A + (size_t)(row0 + m) * K + ss * 8;
    aOff[i] = p * 8;
  }
#pragma unroll
  for (int i = 0; i < 4; ++i) {
    int p = i * 512 + tid;
    int m = p >> 3, slot = p & 7;
    int ss = slot ^ (m & 7);
    int rowB = col0 + m;
    if (EPI == 1 && rowB >= WOPAD) rowB = WOPAD - 1;  // zeroed pad row
    bSrc[i] = B + (size_t)rowB * K + ss * 8;
    bOff[i] = p * 8;
  }

  const int nkt = K >> 6;
  for (int kt = 0; kt < nkt; ++kt) {
    __syncthreads();  // previous iter's ds_reads done before overwrite
#pragma unroll
    for (int i = 0; i < 2; ++i) gl_lds16(aSrc[i] + kt * 64, &As[aOff[i]]);
#pragma unroll
    for (int i = 0; i < 4; ++i) gl_lds16(bSrc[i] + kt * 64, &Bs[bOff[i]]);
    __syncthreads();  // compiler drains vmcnt(0) before barrier -> LDS ready
#pragma unroll
    for (int kk = 0; kk < 2; ++kk) {
      bf16x8 af[4], bf[4];
#pragma unroll
      for (int mi = 0; mi < 4; ++mi) {
        int r = wm * 64 + mi * 16 + l15;
        int sl = (kk * 4 + lhi) ^ (r & 7);
        af[mi] = *(const bf16x8*)((char*)As + r * 128 + sl * 16);
      }
#pragma unroll
      for (int ni = 0; ni < 4; ++ni) {
        int r = wn * 64 + ni * 16 + l15;
        int sl = (kk * 4 + lhi) ^ (r & 7);
        bf[ni] = *(const bf16x8*)((char*)Bs + r * 128 + sl * 16);
      }
#pragma unroll
      for (int mi = 0; mi < 4; ++mi)
#pragma unroll
        for (int ni = 0; ni < 4; ++ni)
          acc[mi][ni] = __builtin_amdgcn_mfma_f32_16x16x32_bf16(af[mi], bf[ni], acc[mi][ni], 0, 0, 0);
    }
  }

  // ---- epilogue ----  C layout: col = lane&15, row = (lane>>4)*4 + reg
  if (EPI == 0) {
#pragma unroll
    for (int mi = 0; mi < 4; ++mi) {
#pragma unroll
      for (int r = 0; r < 4; ++r) {
        int mg = row0 + wm * 64 + mi * 16 + lhi * 4 + r;
#pragma unroll
        for (int ni = 0; ni < 4; ++ni) {
          int ng = col0 + wn * 64 + ni * 16 + l15;
          float v = acc[mi][ni][r];
          v += (ng < NQ) ? biasq[ng] : (ng < NQ + NKVD ? biask[ng - NQ] : biasv[ng - NQ - NKVD]);
          if (ng < NQ + NKVD) {  // RoPE on q and k (wave-uniform branch; 16-aligned regions)
            float partner = __shfl_xor(v, 1);
            int d = ng & 63, p = d >> 1;
            float c = cosT[mg * 32 + p], s = sinT[mg * 32 + p];
            v = (d & 1) ? (partner * s + v * c) : (v * c - partner * s);
          }
          short b16 = f2bf(v);
          if (ng < NQ)              qout[(size_t)mg * NQ + ng] = b16;
          else if (ng < NQ + NKVD)  kout[(size_t)mg * NKVD + (ng - NQ)] = b16;
          else                      vout[(size_t)mg * NKVD + (ng - NQ - NKVD)] = b16;
        }
      }
    }
  } else {
#pragma unroll
    for (int mi = 0; mi < 4; ++mi) {
#pragma unroll
      for (int r = 0; r < 4; ++r) {
        int mg = row0 + wm * 64 + mi * 16 + lhi * 4 + r;
#pragma unroll
        for (int ni = 0; ni < 4; ++ni) {
          int ng = col0 + wn * 64 + ni * 16 + l15;
          if (ng < HID_DIM) out[(size_t)mg * HID_DIM + ng] = acc[mi][ni][r] + bo[ng];
        }
      }
    }
  }
}

// ---------------- sliding-window attention with sinks ----------------
// grid = 2048 blocks: h = bx&63, qblock = bx>>6 (64 queries). 4 waves x 16 queries.
// Per wave: 9 live 16-key tiles covering keys [q0+wq*16-128, q0+wq*16+15].
// (V staging = R10 version: coalesced global reads + scalar ds writes.
//  R11's b64-packed variant broke global coalescing and regressed; reverted.)
__global__ __launch_bounds__(256) void k_attn(
    const short* __restrict__ qb, const short* __restrict__ kb,
    const short* __restrict__ vb, const float* __restrict__ sinks,
    short* __restrict__ attnb) {
  const int h = blockIdx.x & 63;
  const int q0 = (blockIdx.x >> 6) * 64;
  const int tid = threadIdx.x;
  const int lane = tid & 63, wq = tid >> 6;
  const int l15 = lane & 15, lhi = lane >> 4;
  const int hkv = h >> 3;
  const int kstart = q0 - 128;

  // Vt: [d][key] stride 256, chunk-XOR swizzle: element (d,key) lives at
  // Vt[d*256 + (key ^ ((d&7)<<3))]. Swizzle is closed within 64-key blocks,
  // so the zero region [192,256) maps onto itself.
  __shared__ short Vt[64 * 256];
  __shared__ short Plds[4][16 * 168];     // per-wave P, stride 168 (bank-balanced)

  // zero-fill keys [192,256) for every d row (covers PV reads past live keys)
  {
    int d = tid >> 2;
    int k16 = (tid & 3) * 16;
#pragma unroll
    for (int j = 0; j < 16; j += 4)
      *(short4*)&Vt[d * 256 + 192 + k16 + j] = (short4){0, 0, 0, 0};
  }

  // stage V^T: Vt[d][key] = vb[kstart+key][hkv*64+d], key in [0,192)
  {
    int krow = tid >> 2;            // 0..63
    int dbase = (tid & 3) * 16;
#pragma unroll
    for (int rep = 0; rep < 3; ++rep) {
      int key = rep * 64 + krow;
      int gk = kstart + key;
      int gkc = gk < 0 ? 0 : gk;    // clamped loads are masked later (P=0)
      const short* src = vb + (size_t)gkc * NKVD + hkv * 64 + dbase;
      uint4 v0 = *(const uint4*)(src);
      uint4 v1 = *(const uint4*)(src + 8);
      uint32_t w[8] = {v0.x, v0.y, v0.z, v0.w, v1.x, v1.y, v1.z, v1.w};
#pragma unroll
      for (int i = 0; i < 8; ++i) {
        int d0 = dbase + 2 * i, d1 = dbase + 2 * i + 1;
        Vt[d0 * 256 + (key ^ ((d0 & 7) << 3))] = (short)(w[i] & 0xffffu);
        Vt[d1 * 256 + (key ^ ((d1 & 7) << 3))] = (short)(w[i] >> 16);
      }
    }
  }

  // Q fragments (A-frag: row = lane&15, k = (lane>>4)*8, two 32-wide k halves)
  int qrow = q0 + wq * 16 + l15;
  bf16x8 aq[2];
#pragma unroll
  for (int kk = 0; kk < 2; ++kk)
    aq[kk] = *(const bf16x8*)(qb + (size_t)qrow * NQ + h * 64 + kk * 32 + lhi * 8);

  // S = Q K^T over 9 live tiles
  f32x4 sacc[9];
#pragma unroll
  for (int ni = 0; ni < 9; ++ni) {
    int key = kstart + (wq + ni) * 16 + l15;
    int keyc = key < 0 ? 0 : key;
    const short* kp = kb + (size_t)keyc * NKVD + hkv * 64;
    bf16x8 b0 = *(const bf16x8*)(kp + lhi * 8);
    bf16x8 b1 = *(const bf16x8*)(kp + 32 + lhi * 8);
    f32x4 z = (f32x4){0.f, 0.f, 0.f, 0.f};
    z = __builtin_amdgcn_mfma_f32_16x16x32_bf16(aq[0], b0, z, 0, 0, 0);
    z = __builtin_amdgcn_mfma_f32_16x16x32_bf16(aq[1], b1, z, 0, 0, 0);
    sacc[ni] = z;
  }

  float snk = sinks[h];
  // mask + scale + row max
  float mx[4] = {NEGINF, NEGINF, NEGINF, NEGINF};
#pragma unroll
  for (int ni = 0; ni < 9; ++ni) {
    int j = kstart + (wq + ni) * 16 + l15;
#pragma unroll
    for (int r = 0; r < 4; ++r) {
      int iq = q0 + wq * 16 + lhi * 4 + r;
      float sv = sacc[ni][r] * ATT_SCALE;
      bool valid = (j >= 0) && (j <= iq) && (iq - j < 128);
      sv = valid ? sv : NEGINF;
      sacc[ni][r] = sv;
      mx[r] = fmaxf(mx[r], sv);
    }
  }
#pragma unroll
  for (int r = 0; r < 4; ++r) {
    float m = mx[r];
    m = fmaxf(m, __shfl_xor(m, 1));
    m = fmaxf(m, __shfl_xor(m, 2));
    m = fmaxf(m, __shfl_xor(m, 4));
    m = fmaxf(m, __shfl_xor(m, 8));
    mx[r] = fmaxf(m, snk);
  }
  float sm[4] = {0.f, 0.f, 0.f, 0.f};
#pragma unroll
  for (int ni = 0; ni < 9; ++ni)
#pragma unroll
    for (int r = 0; r < 4; ++r) {
      float p = __expf(sacc[ni][r] - mx[r]);  // exp(-1e30)=0 handles masked
      sacc[ni][r] = p;
      sm[r] += p;
    }
  float inv[4];
#pragma unroll
  for (int r = 0; r < 4; ++r) {
    float s = sm[r];
    s += __shfl_xor(s, 1);
    s += __shfl_xor(s, 2);
    s += __shfl_xor(s, 4);
    s += __shfl_xor(s, 8);
    s += __expf(snk - mx[r]);
    inv[r] = 1.0f / s;
  }

  // P -> LDS (bf16), plus zero-pad tile (cols 144..159) so PV runs 5 K-steps
  short* pw = &Plds[wq][0];
#pragma unroll
  for (int ni = 0; ni < 9; ++ni)
#pragma unroll
    for (int r = 0; r < 4; ++r)
      pw[(lhi * 4 + r) * 168 + ni * 16 + l15] = f2bf(sacc[ni][r]);
#pragma unroll
  for (int r = 0; r < 4; ++r)
    pw[(lhi * 4 + r) * 168 + 144 + l15] = 0;

  __syncthreads();  // Vt staged by all waves; P writes drained

  // O = P V : 16q x 64d per wave, K = 160 (padded)
  f32x4 oacc[4];
#pragma unroll
  for (int nt = 0; nt < 4; ++nt) oacc[nt] = (f32x4){0.f, 0.f, 0.f, 0.f};
  const short* pr = &Plds[wq][0];
#pragma unroll
  for (int ks = 0; ks < 5; ++ks) {
    bf16x8 pf = *(const bf16x8*)(pr + l15 * 168 + ks * 32 + lhi * 8);
#pragma unroll
    for (int nt = 0; nt < 4; ++nt) {
      int d = nt * 16 + l15;
      int keyidx = wq * 16 + ks * 32 + lhi * 8;           // 8-aligned
      bf16x8 vf = *(const bf16x8*)(&Vt[d * 256 + (keyidx ^ ((d & 7) << 3))]);
      oacc[nt] = __builtin_amdgcn_mfma_f32_16x16x32_bf16(pf, vf, oacc[nt], 0, 0, 0);
    }
  }

#pragma unroll
  for (int nt = 0; nt < 4; ++nt)
#pragma unroll
    for (int r = 0; r < 4; ++r) {
      int iq = q0 + wq * 16 + lhi * 4 + r;
      int d = nt * 16 + l15;
      attnb[(size_t)iq * NQ + h * 64 + d] = f2bf(oacc[nt][r] * inv[r]);
    }
}

// ---------------- launch ----------------
extern "C" void kernel_launch(void* const* d_in, const int* in_sizes, int n_in,
                              void* d_out, int out_size, void* d_ws, size_t ws_size,
                              hipStream_t stream) {
  const float* x     = (const float*)d_in[0];
  const float* cosT  = (const float*)d_in[1];
  const float* sinT  = (const float*)d_in[2];
  const float* Wq    = (const float*)d_in[3];
  const float* bq    = (const float*)d_in[4];
  const float* Wk    = (const float*)d_in[5];
  const float* bk    = (const float*)d_in[6];
  const float* Wv    = (const float*)d_in[7];
  const float* bv    = (const float*)d_in[8];
  const float* Wo    = (const float*)d_in[9];
  const float* bo    = (const float*)d_in[10];
  const float* sinks = (const float*)d_in[11];
  float* out = (float*)d_out;

  // workspace layout (bf16 shorts), total ~103.2 MB
  short* xb    = (short*)d_ws;
  short* wqkvb = xb + (size_t)S_LEN * HID_DIM;                 // [5120][2880]
  short* wob   = wqkvb + (size_t)NQKV * HID_DIM;               // [2944][4096]
  short* qbuf  = wob + (size_t)WOPAD * NQ;                     // [2048][4096]
  short* kbuf  = qbuf + (size_t)S_LEN * NQ;                    // [2048][512]
  short* vbuf  = kbuf + (size_t)S_LEN * NKVD;                  // [2048][512]
  short* attnb = vbuf + (size_t)S_LEN * NKVD;                  // [2048][4096]

  k_prep<<<31936, 256, 0, stream>>>(x, xb, Wq, Wk, Wv, Wo, wqkvb, wob);

  k_gemm<0><<<dim3(NQKV / 256, S_LEN / 128), 512, 0, stream>>>(
      xb, wqkvb, HID_DIM, bq, bk, bv, cosT, sinT, qbuf, kbuf, vbuf, nullptr, nullptr);

  k_attn<<<(S_LEN / 64) * NHEAD, 256, 0, stream>>>(qbuf, kbuf, vbuf, sinks, attnb);

  k_gemm<1><<<dim3(12, S_LEN / 128), 512, 0, stream>>>(
      attnb, wob, NQ, nullptr, nullptr, nullptr, nullptr, nullptr,
      nullptr, nullptr, nullptr, bo, out);
}

// Round 14
// 214.381 us; speedup vs baseline: 1.2429x; 1.2429x over previous
//
#include <hip/hip_runtime.h>
#include <stdint.h>

#define S_LEN   2048
#define HID_DIM 2880
#define NHEAD   64
#define NKVH    8
#define DHEAD   64
#define NQ      4096      // H*D
#define NKVD    512       // HKV*D
#define NQKV    5120      // NQ + 2*NKVD
#define WOPAD   2944      // 2880 padded to 23*128
#define ATT_SCALE 0.125f
#define NEGINF  (-1e30f)

typedef __attribute__((ext_vector_type(8))) short bf16x8;
typedef __attribute__((ext_vector_type(4))) float f32x4;

typedef __attribute__((address_space(3))) uint32_t lds_u32;
typedef const __attribute__((address_space(1))) uint32_t glb_u32;

// async global->LDS, 16B per lane. LDS dest semantics: wave-uniform base +
// lane*16 (per-lane l must be contiguous in lane order). Global src IS per-lane.
__device__ __forceinline__ void gl_lds16(const short* g, short* l) {
  __builtin_amdgcn_global_load_lds((glb_u32*)(uintptr_t)g,
                                   (lds_u32*)(uint32_t)(uintptr_t)l, 16, 0, 0);
}

__device__ __forceinline__ short f2bf(float f) {
  union { float f; uint32_t u; } c; c.f = f;
  uint32_t u = c.u;
  return (short)((u + 0x7FFFu + ((u >> 16) & 1u)) >> 16);  // RNE
}

// ---------------- fused prep: cvt x + 4 transpose-converts, one launch ----------------
// 1D grid, 256 threads. Regions (block ranges):
//   [0,5760)        cvt_x: 5760*256 float4 = 2048*2880 f32 -> bf16
//   [5760,17280)    Wq  [2880][4096] -> wqkvb[0..4096)[2880]      (90 x 128 tiles)
//   [17280,18720)   Wk  [2880][512]  -> wqkvb[4096..4608)[2880]   (90 x 16)
//   [18720,20160)   Wv  [2880][512]  -> wqkvb[4608..5120)[2880]   (90 x 16)
//   [20160,31936)   Wo  [4096][2880] -> wob[0..2944)[4096]        (128 x 92, pad rows zeroed)
__global__ __launch_bounds__(256) void k_prep(
    const float* __restrict__ x, short* __restrict__ xb,
    const float* __restrict__ Wq, const float* __restrict__ Wk,
    const float* __restrict__ Wv, const float* __restrict__ Wo,
    short* __restrict__ wqkvb, short* __restrict__ wob) {
  int b = blockIdx.x;
  if (b < 5760) {
    int i = b * 256 + threadIdx.x;
    float4 v = ((const float4*)x)[i];
    short4 o;
    o.x = f2bf(v.x); o.y = f2bf(v.y); o.z = f2bf(v.z); o.w = f2bf(v.w);
    ((short4*)xb)[i] = o;
    return;
  }
  b -= 5760;
  const float* src; short* dst; int K, N, tk;
  if (b < 11520) {
    src = Wq; dst = wqkvb; K = 2880; N = 4096; tk = 90;
  } else if (b < 11520 + 1440) {
    b -= 11520;
    src = Wk; dst = wqkvb + (size_t)NQ * HID_DIM; K = 2880; N = 512; tk = 90;
  } else if (b < 11520 + 2880) {
    b -= 11520 + 1440;
    src = Wv; dst = wqkvb + (size_t)(NQ + NKVD) * HID_DIM; K = 2880; N = 512; tk = 90;
  } else {
    b -= 11520 + 2880;
    src = Wo; dst = wob; K = 4096; N = 2880; tk = 128;
  }
  int k0 = (b % tk) * 32, n0 = (b / tk) * 32;
  __shared__ float tile[32][33];
  int tx = threadIdx.x & 31, ty = threadIdx.x >> 5;
#pragma unroll
  for (int j = 0; j < 4; ++j) {
    int n = n0 + tx, k = k0 + ty + j * 8;
    tile[ty + j * 8][tx] = (n < N) ? src[(size_t)k * N + n] : 0.f;
  }
  __syncthreads();
#pragma unroll
  for (int j = 0; j < 4; ++j) {
    int n = n0 + ty + j * 8;
    dst[(size_t)n * K + k0 + tx] = f2bf(tile[tx][ty + j * 8]);
  }
}

// ------------- qkv GEMM: 128x160 tile, BK=64, 512 threads = 8 waves (4x2) -------------
// Wave = 32x80 (acc[2][5]). Grid 32x16 = 512 blocks = exactly 2.0/CU, zero
// tail (R13 showed <1.5/CU collapses the staging issue rate; R10 showed the
// ~12.8 TB/s staging ceiling at >=2.5/CU). Staged bytes x0.90 vs 128x128.
// LDS 36KB single buffer, 2-barrier loop; same XOR swizzle both ways.
// Epilogue: bias + RoPE + split bf16 q/k/v stores.
__global__ __launch_bounds__(512) void k_gemm_qkv(
    const short* __restrict__ A, const short* __restrict__ B,
    const float* __restrict__ biasq, const float* __restrict__ biask,
    const float* __restrict__ biasv,
    const float* __restrict__ cosT, const float* __restrict__ sinT,
    short* __restrict__ qout, short* __restrict__ kout, short* __restrict__ vout) {
  const int K = HID_DIM;
  const int tid = threadIdx.x;
  const int lane = tid & 63, wid = tid >> 6;
  const int wm = wid >> 1, wn = wid & 1;     // 4 x 2 wave grid; wave = 32 x 80
  const int l15 = lane & 15, lhi = lane >> 4;
  const int row0 = blockIdx.y * 128, col0 = blockIdx.x * 160;

  __shared__ short As[128 * 64];   // 16KB
  __shared__ short Bs[160 * 64];   // 20KB

  f32x4 acc[2][5];
#pragma unroll
  for (int i = 0; i < 2; ++i)
#pragma unroll
    for (int j = 0; j < 5; ++j) acc[i][j] = (f32x4){0.f, 0.f, 0.f, 0.f};

  // staging coords; global source slot swizzled ss = slot ^ (m&7), LDS linear.
  // A: 1024 16B-chunks (2/thread). B: 1280 chunks (2/thread + tid<256 a 3rd).
  const short* aSrc[2]; int aOff[2];
  const short* bSrc[2]; int bOff[2];
#pragma unroll
  for (int i = 0; i < 2; ++i) {
    int p = i * 512 + tid;
    int m = p >> 3, slot = p & 7;
    int ss = slot ^ (m & 7);
    aSrc[i] = A + (size_t)(row0 + m) * K + ss * 8;
    aOff[i] = p * 8;
    bSrc[i] = B + (size_t)(col0 + m) * K + ss * 8;
    bOff[i] = p * 8;
  }
  const short* bSrc2 = nullptr; int bOff2 = 0;
  if (tid < 256) {
    int p = 1024 + tid;
    int m = p >> 3, slot = p & 7;
    int ss = slot ^ (m & 7);
    bSrc2 = B + (size_t)(col0 + m) * K + ss * 8;
    bOff2 = p * 8;
  }

  const int nkt = K >> 6;   // 45
  for (int kt = 0; kt < nkt; ++kt) {
    __syncthreads();  // previous iter's ds_reads done before overwrite
#pragma unroll
    for (int i = 0; i < 2; ++i) gl_lds16(aSrc[i] + kt * 64, &As[aOff[i]]);
#pragma unroll
    for (int i = 0; i < 2; ++i) gl_lds16(bSrc[i] + kt * 64, &Bs[bOff[i]]);
    if (tid < 256) gl_lds16(bSrc2 + kt * 64, &Bs[bOff2]);
    __syncthreads();  // compiler drains vmcnt(0) before barrier -> LDS ready
#pragma unroll
    for (int kk = 0; kk < 2; ++kk) {
      bf16x8 af[2], bf[5];
#pragma unroll
      for (int mi = 0; mi < 2; ++mi) {
        int r = wm * 32 + mi * 16 + l15;
        int sl = (kk * 4 + lhi) ^ (r & 7);
        af[mi] = *(const bf16x8*)((char*)As + r * 128 + sl * 16);
      }
#pragma unroll
      for (int ni = 0; ni < 5; ++ni) {
        int r = wn * 80 + ni * 16 + l15;
        int sl = (kk * 4 + lhi) ^ (r & 7);
        bf[ni] = *(const bf16x8*)((char*)Bs + r * 128 + sl * 16);
      }
#pragma unroll
      for (int mi = 0; mi < 2; ++mi)
#pragma unroll
        for (int ni = 0; ni < 5; ++ni)
          acc[mi][ni] = __builtin_amdgcn_mfma_f32_16x16x32_bf16(af[mi], bf[ni], acc[mi][ni], 0, 0, 0);
    }
  }

  // epilogue; C layout: col = lane&15, row = (lane>>4)*4 + reg.
  // All region boundaries (4096, 4608) are 16-aligned and each fragment's ng
  // span is a 16-aligned l15-run -> branches wave-uniform.
#pragma unroll
  for (int mi = 0; mi < 2; ++mi) {
#pragma unroll
    for (int r = 0; r < 4; ++r) {
      int mg = row0 + wm * 32 + mi * 16 + lhi * 4 + r;
#pragma unroll
      for (int ni = 0; ni < 5; ++ni) {
        int ng = col0 + wn * 80 + ni * 16 + l15;
        float v = acc[mi][ni][r];
        v += (ng < NQ) ? biasq[ng] : (ng < NQ + NKVD ? biask[ng - NQ] : biasv[ng - NQ - NKVD]);
        if (ng < NQ + NKVD) {  // RoPE on q and k
          float partner = __shfl_xor(v, 1);
          int d = ng & 63, p = d >> 1;
          float c = cosT[mg * 32 + p], s = sinT[mg * 32 + p];
          v = (d & 1) ? (partner * s + v * c) : (v * c - partner * s);
        }
        short b16 = f2bf(v);
        if (ng < NQ)              qout[(size_t)mg * NQ + ng] = b16;
        else if (ng < NQ + NKVD)  kout[(size_t)mg * NKVD + (ng - NQ)] = b16;
        else                      vout[(size_t)mg * NKVD + (ng - NQ - NKVD)] = b16;
      }
    }
  }
}

// ------------- out-proj GEMM: exact R10 config (control) -------------
// 128x128 tile, BK=64, 512 threads = 8 waves (2x4), wave 64x32 (acc[4][2]).
// Single 32KB LDS, 2-barrier loop. Bias + f32 store guarded n<2880.
__global__ __launch_bounds__(512) void k_gemm_o(
    const short* __restrict__ A, const short* __restrict__ B,
    const float* __restrict__ bo, float* __restrict__ out) {
  const int K = NQ;
  const int tid = threadIdx.x;
  const int lane = tid & 63, wid = tid >> 6;
  const int wm = wid >> 2, wn = wid & 3;     // 2 x 4 wave grid
  const int l15 = lane & 15, lhi = lane >> 4;
  const int row0 = blockIdx.y * 128, col0 = blockIdx.x * 128;

  __shared__ short As[128 * 64];
  __shared__ short Bs[128 * 64];

  f32x4 acc[4][2];
#pragma unroll
  for (int i = 0; i < 4; ++i)
#pragma unroll
    for (int j = 0; j < 2; ++j) acc[i][j] = (f32x4){0.f, 0.f, 0.f, 0.f};

  const short* aSrc[2];
  const short* bSrc[2];
  int dOff[2];
#pragma unroll
  for (int i = 0; i < 2; ++i) {
    int p = i * 512 + tid;
    int m = p >> 3, slot = p & 7;
    int ss = slot ^ (m & 7);
    aSrc[i] = A + (size_t)(row0 + m) * K + ss * 8;
    bSrc[i] = B + (size_t)(col0 + m) * K + ss * 8;
    dOff[i] = p * 8;
  }

  const int nkt = K >> 6;
  for (int kt = 0; kt < nkt; ++kt) {
    __syncthreads();
#pragma unroll
    for (int i = 0; i < 2; ++i) gl_lds16(aSrc[i] + kt * 64, &As[dOff[i]]);
#pragma unroll
    for (int i = 0; i < 2; ++i) gl_lds16(bSrc[i] + kt * 64, &Bs[dOff[i]]);
    __syncthreads();
#pragma unroll
    for (int kk = 0; kk < 2; ++kk) {
      bf16x8 af[4], bf[2];
#pragma unroll
      for (int mi = 0; mi < 4; ++mi) {
        int r = wm * 64 + mi * 16 + l15;
        int sl = (kk * 4 + lhi) ^ (r & 7);
        af[mi] = *(const bf16x8*)((char*)As + r * 128 + sl * 16);
      }
#pragma unroll
      for (int ni = 0; ni < 2; ++ni) {
        int r = wn * 32 + ni * 16 + l15;
        int sl = (kk * 4 + lhi) ^ (r & 7);
        bf[ni] = *(const bf16x8*)((char*)Bs + r * 128 + sl * 16);
      }
#pragma unroll
      for (int mi = 0; mi < 4; ++mi)
#pragma unroll
        for (int ni = 0; ni < 2; ++ni)
          acc[mi][ni] = __builtin_amdgcn_mfma_f32_16x16x32_bf16(af[mi], bf[ni], acc[mi][ni], 0, 0, 0);
    }
  }

#pragma unroll
  for (int mi = 0; mi < 4; ++mi) {
#pragma unroll
    for (int r = 0; r < 4; ++r) {
      int mg = row0 + wm * 64 + mi * 16 + lhi * 4 + r;
#pragma unroll
      for (int ni = 0; ni < 2; ++ni) {
        int ng = col0 + wn * 32 + ni * 16 + l15;
        if (ng < HID_DIM) out[(size_t)mg * HID_DIM + ng] = acc[mi][ni][r] + bo[ng];
      }
    }
  }
}

// ---------------- sliding-window attention with sinks ----------------
// grid = 2048 blocks: h = bx&63, qblock = bx>>6 (64 queries). 4 waves x 16 queries.
// Per wave: 9 live 16-key tiles covering keys [q0+wq*16-128, q0+wq*16+15].
// (V staging = R10 version: coalesced global reads + scalar ds writes.
//  R11's b64-packed variant broke global coalescing and regressed; reverted.)
__global__ __launch_bounds__(256) void k_attn(
    const short* __restrict__ qb, const short* __restrict__ kb,
    const short* __restrict__ vb, const float* __restrict__ sinks,
    short* __restrict__ attnb) {
  const int h = blockIdx.x & 63;
  const int q0 = (blockIdx.x >> 6) * 64;
  const int tid = threadIdx.x;
  const int lane = tid & 63, wq = tid >> 6;
  const int l15 = lane & 15, lhi = lane >> 4;
  const int hkv = h >> 3;
  const int kstart = q0 - 128;

  // Vt: [d][key] stride 256, chunk-XOR swizzle: element (d,key) lives at
  // Vt[d*256 + (key ^ ((d&7)<<3))]. Swizzle is closed within 64-key blocks,
  // so the zero region [192,256) maps onto itself.
  __shared__ short Vt[64 * 256];
  __shared__ short Plds[4][16 * 168];     // per-wave P, stride 168 (bank-balanced)

  // zero-fill keys [192,256) for every d row (covers PV reads past live keys)
  {
    int d = tid >> 2;
    int k16 = (tid & 3) * 16;
#pragma unroll
    for (int j = 0; j < 16; j += 4)
      *(short4*)&Vt[d * 256 + 192 + k16 + j] = (short4){0, 0, 0, 0};
  }

  // stage V^T: Vt[d][key] = vb[kstart+key][hkv*64+d], key in [0,192)
  {
    int krow = tid >> 2;            // 0..63
    int dbase = (tid & 3) * 16;
#pragma unroll
    for (int rep = 0; rep < 3; ++rep) {
      int key = rep * 64 + krow;
      int gk = kstart + key;
      int gkc = gk < 0 ? 0 : gk;    // clamped loads are masked later (P=0)
      const short* src = vb + (size_t)gkc * NKVD + hkv * 64 + dbase;
      uint4 v0 = *(const uint4*)(src);
      uint4 v1 = *(const uint4*)(src + 8);
      uint32_t w[8] = {v0.x, v0.y, v0.z, v0.w, v1.x, v1.y, v1.z, v1.w};
#pragma unroll
      for (int i = 0; i < 8; ++i) {
        int d0 = dbase + 2 * i, d1 = dbase + 2 * i + 1;
        Vt[d0 * 256 + (key ^ ((d0 & 7) << 3))] = (short)(w[i] & 0xffffu);
        Vt[d1 * 256 + (key ^ ((d1 & 7) << 3))] = (short)(w[i] >> 16);
      }
    }
  }

  // Q fragments (A-frag: row = lane&15, k = (lane>>4)*8, two 32-wide k halves)
  int qrow = q0 + wq * 16 + l15;
  bf16x8 aq[2];
#pragma unroll
  for (int kk = 0; kk < 2; ++kk)
    aq[kk] = *(const bf16x8*)(qb + (size_t)qrow * NQ + h * 64 + kk * 32 + lhi * 8);

  // S = Q K^T over 9 live tiles
  f32x4 sacc[9];
#pragma unroll
  for (int ni = 0; ni < 9; ++ni) {
    int key = kstart + (wq + ni) * 16 + l15;
    int keyc = key < 0 ? 0 : key;
    const short* kp = kb + (size_t)keyc * NKVD + hkv * 64;
    bf16x8 b0 = *(const bf16x8*)(kp + lhi * 8);
    bf16x8 b1 = *(const bf16x8*)(kp + 32 + lhi * 8);
    f32x4 z = (f32x4){0.f, 0.f, 0.f, 0.f};
    z = __builtin_amdgcn_mfma_f32_16x16x32_bf16(aq[0], b0, z, 0, 0, 0);
    z = __builtin_amdgcn_mfma_f32_16x16x32_bf16(aq[1], b1, z, 0, 0, 0);
    sacc[ni] = z;
  }

  float snk = sinks[h];
  // mask + scale + row max
  float mx[4] = {NEGINF, NEGINF, NEGINF, NEGINF};
#pragma unroll
  for (int ni = 0; ni < 9; ++ni) {
    int j = kstart + (wq + ni) * 16 + l15;
#pragma unroll
    for (int r = 0; r < 4; ++r) {
      int iq = q0 + wq * 16 + lhi * 4 + r;
      float sv = sacc[ni][r] * ATT_SCALE;
      bool valid = (j >= 0) && (j <= iq) && (iq - j < 128);
      sv = valid ? sv : NEGINF;
      sacc[ni][r] = sv;
      mx[r] = fmaxf(mx[r], sv);
    }
  }
#pragma unroll
  for (int r = 0; r < 4; ++r) {
    float m = mx[r];
    m = fmaxf(m, __shfl_xor(m, 1));
    m = fmaxf(m, __shfl_xor(m, 2));
    m = fmaxf(m, __shfl_xor(m, 4));
    m = fmaxf(m, __shfl_xor(m, 8));
    mx[r] = fmaxf(m, snk);
  }
  float sm[4] = {0.f, 0.f, 0.f, 0.f};
#pragma unroll
  for (int ni = 0; ni < 9; ++ni)
#pragma unroll
    for (int r = 0; r < 4; ++r) {
      float p = __expf(sacc[ni][r] - mx[r]);  // exp(-1e30)=0 handles masked
      sacc[ni][r] = p;
      sm[r] += p;
    }
  float inv[4];
#pragma unroll
  for (int r = 0; r < 4; ++r) {
    float s = sm[r];
    s += __shfl_xor(s, 1);
    s += __shfl_xor(s, 2);
    s += __shfl_xor(s, 4);
    s += __shfl_xor(s, 8);
    s += __expf(snk - mx[r]);
    inv[r] = 1.0f / s;
  }

  // P -> LDS (bf16), plus zero-pad tile (cols 144..159) so PV runs 5 K-steps
  short* pw = &Plds[wq][0];
#pragma unroll
  for (int ni = 0; ni < 9; ++ni)
#pragma unroll
    for (int r = 0; r < 4; ++r)
      pw[(lhi * 4 + r) * 168 + ni * 16 + l15] = f2bf(sacc[ni][r]);
#pragma unroll
  for (int r = 0; r < 4; ++r)
    pw[(lhi * 4 + r) * 168 + 144 + l15] = 0;

  __syncthreads();  // Vt staged by all waves; P writes drained

  // O = P V : 16q x 64d per wave, K = 160 (padded)
  f32x4 oacc[4];
#pragma unroll
  for (int nt = 0; nt < 4; ++nt) oacc[nt] = (f32x4){0.f, 0.f, 0.f, 0.f};
  const short* pr = &Plds[wq][0];
#pragma unroll
  for (int ks = 0; ks < 5; ++ks) {
    bf16x8 pf = *(const bf16x8*)(pr + l15 * 168 + ks * 32 + lhi * 8);
#pragma unroll
    for (int nt = 0; nt < 4; ++nt) {
      int d = nt * 16 + l15;
      int keyidx = wq * 16 + ks * 32 + lhi * 8;           // 8-aligned
      bf16x8 vf = *(const bf16x8*)(&Vt[d * 256 + (keyidx ^ ((d & 7) << 3))]);
      oacc[nt] = __builtin_amdgcn_mfma_f32_16x16x32_bf16(pf, vf, oacc[nt], 0, 0, 0);
    }
  }

#pragma unroll
  for (int nt = 0; nt < 4; ++nt)
#pragma unroll
    for (int r = 0; r < 4; ++r) {
      int iq = q0 + wq * 16 + lhi * 4 + r;
      int d = nt * 16 + l15;
      attnb[(size_t)iq * NQ + h * 64 + d] = f2bf(oacc[nt][r] * inv[r]);
    }
}

// ---------------- launch ----------------
extern "C" void kernel_launch(void* const* d_in, const int* in_sizes, int n_in,
                              void* d_out, int out_size, void* d_ws, size_t ws_size,
                              hipStream_t stream) {
  const float* x     = (const float*)d_in[0];
  const float* cosT  = (const float*)d_in[1];
  const float* sinT  = (const float*)d_in[2];
  const float* Wq    = (const float*)d_in[3];
  const float* bq    = (const float*)d_in[4];
  const float* Wk    = (const float*)d_in[5];
  const float* bk    = (const float*)d_in[6];
  const float* Wv    = (const float*)d_in[7];
  const float* bv    = (const float*)d_in[8];
  const float* Wo    = (const float*)d_in[9];
  const float* bo    = (const float*)d_in[10];
  const float* sinks = (const float*)d_in[11];
  float* out = (float*)d_out;

  // workspace layout (bf16 shorts), total ~103.2 MB
  short* xb    = (short*)d_ws;
  short* wqkvb = xb + (size_t)S_LEN * HID_DIM;                 // [5120][2880]
  short* wob   = wqkvb + (size_t)NQKV * HID_DIM;               // [2944][4096]
  short* qbuf  = wob + (size_t)WOPAD * NQ;                     // [2048][4096]
  short* kbuf  = qbuf + (size_t)S_LEN * NQ;                    // [2048][512]
  short* vbuf  = kbuf + (size_t)S_LEN * NKVD;                  // [2048][512]
  short* attnb = vbuf + (size_t)S_LEN * NKVD;                  // [2048][4096]

  k_prep<<<31936, 256, 0, stream>>>(x, xb, Wq, Wk, Wv, Wo, wqkvb, wob);

  k_gemm_qkv<<<dim3(NQKV / 160, S_LEN / 128), 512, 0, stream>>>(
      xb, wqkvb, bq, bk, bv, cosT, sinT, qbuf, kbuf, vbuf);

  k_attn<<<(S_LEN / 64) * NHEAD, 256, 0, stream>>>(qbuf, kbuf, vbuf, sinks, attnb);

  k_gemm_o<<<dim3(WOPAD / 128, S_LEN / 128), 512, 0, stream>>>(
      attnb, wob, bo, out);
}

// Round 15
// 209.583 us; speedup vs baseline: 1.2714x; 1.0229x over previous
//
#include <hip/hip_runtime.h>
#include <stdint.h>

#define S_LEN   2048
#define HID_DIM 2880
#define NHEAD   64
#define NKVH    8
#define DHEAD   64
#define NQ      4096      // H*D
#define NKVD    512       // HKV*D
#define NQKV    5120      // NQ + 2*NKVD
#define WOPAD   2944      // 2880 padded to 23*128
#define ATT_SCALE 0.125f
#define NEGINF  (-1e30f)

typedef __attribute__((ext_vector_type(8))) short bf16x8;
typedef __attribute__((ext_vector_type(4))) float f32x4;

typedef __attribute__((address_space(3))) uint32_t lds_u32;
typedef const __attribute__((address_space(1))) uint32_t glb_u32;

// async global->LDS, 16B per lane. LDS dest semantics: wave-uniform base +
// lane*16 (per-lane l must be contiguous in lane order). Global src IS per-lane.
__device__ __forceinline__ void gl_lds16(const short* g, short* l) {
  __builtin_amdgcn_global_load_lds((glb_u32*)(uintptr_t)g,
                                   (lds_u32*)(uint32_t)(uintptr_t)l, 16, 0, 0);
}

__device__ __forceinline__ short f2bf(float f) {
  union { float f; uint32_t u; } c; c.f = f;
  uint32_t u = c.u;
  return (short)((u + 0x7FFFu + ((u >> 16) & 1u)) >> 16);  // RNE
}

// ---------------- fused prep: cvt x + 4 transpose-converts, one launch ----------------
// 1D grid, 256 threads. Regions (block ranges):
//   [0,5760)        cvt_x: 5760*256 float4 = 2048*2880 f32 -> bf16
//   [5760,17280)    Wq  [2880][4096] -> wqkvb[0..4096)[2880]      (90 x 128 tiles)
//   [17280,18720)   Wk  [2880][512]  -> wqkvb[4096..4608)[2880]   (90 x 16)
//   [18720,20160)   Wv  [2880][512]  -> wqkvb[4608..5120)[2880]   (90 x 16)
//   [20160,31936)   Wo  [4096][2880] -> wob[0..2944)[4096]        (128 x 92, pad rows zeroed)
__global__ __launch_bounds__(256) void k_prep(
    const float* __restrict__ x, short* __restrict__ xb,
    const float* __restrict__ Wq, const float* __restrict__ Wk,
    const float* __restrict__ Wv, const float* __restrict__ Wo,
    short* __restrict__ wqkvb, short* __restrict__ wob) {
  int b = blockIdx.x;
  if (b < 5760) {
    int i = b * 256 + threadIdx.x;
    float4 v = ((const float4*)x)[i];
    short4 o;
    o.x = f2bf(v.x); o.y = f2bf(v.y); o.z = f2bf(v.z); o.w = f2bf(v.w);
    ((short4*)xb)[i] = o;
    return;
  }
  b -= 5760;
  const float* src; short* dst; int K, N, tk;
  if (b < 11520) {
    src = Wq; dst = wqkvb; K = 2880; N = 4096; tk = 90;
  } else if (b < 11520 + 1440) {
    b -= 11520;
    src = Wk; dst = wqkvb + (size_t)NQ * HID_DIM; K = 2880; N = 512; tk = 90;
  } else if (b < 11520 + 2880) {
    b -= 11520 + 1440;
    src = Wv; dst = wqkvb + (size_t)(NQ + NKVD) * HID_DIM; K = 2880; N = 512; tk = 90;
  } else {
    b -= 11520 + 2880;
    src = Wo; dst = wob; K = 4096; N = 2880; tk = 128;
  }
  int k0 = (b % tk) * 32, n0 = (b / tk) * 32;
  __shared__ float tile[32][33];
  int tx = threadIdx.x & 31, ty = threadIdx.x >> 5;
#pragma unroll
  for (int j = 0; j < 4; ++j) {
    int n = n0 + tx, k = k0 + ty + j * 8;
    tile[ty + j * 8][tx] = (n < N) ? src[(size_t)k * N + n] : 0.f;
  }
  __syncthreads();
#pragma unroll
  for (int j = 0; j < 4; ++j) {
    int n = n0 + ty + j * 8;
    dst[(size_t)n * K + k0 + tx] = f2bf(tile[tx][ty + j * 8]);
  }
}

// ------------- qkv GEMM: 128x160 tile, BK=64, 512 threads = 8 waves (4x2) -------------
// Wave = 32x80 (acc[2][5]). Grid 32x16 = 512 blocks = exactly 2.0/CU, zero
// tail. Measured (R14): 76.7us at the ~11.2 TB/s staging service ceiling.
// LDS 36KB single buffer, 2-barrier loop; XOR swizzle both ways.
// Epilogue: bias + RoPE + split bf16 q/k/v stores. UNCHANGED (control).
__global__ __launch_bounds__(512) void k_gemm_qkv(
    const short* __restrict__ A, const short* __restrict__ B,
    const float* __restrict__ biasq, const float* __restrict__ biask,
    const float* __restrict__ biasv,
    const float* __restrict__ cosT, const float* __restrict__ sinT,
    short* __restrict__ qout, short* __restrict__ kout, short* __restrict__ vout) {
  const int K = HID_DIM;
  const int tid = threadIdx.x;
  const int lane = tid & 63, wid = tid >> 6;
  const int wm = wid >> 1, wn = wid & 1;     // 4 x 2 wave grid; wave = 32 x 80
  const int l15 = lane & 15, lhi = lane >> 4;
  const int row0 = blockIdx.y * 128, col0 = blockIdx.x * 160;

  __shared__ short As[128 * 64];   // 16KB
  __shared__ short Bs[160 * 64];   // 20KB

  f32x4 acc[2][5];
#pragma unroll
  for (int i = 0; i < 2; ++i)
#pragma unroll
    for (int j = 0; j < 5; ++j) acc[i][j] = (f32x4){0.f, 0.f, 0.f, 0.f};

  const short* aSrc[2]; int aOff[2];
  const short* bSrc[2]; int bOff[2];
#pragma unroll
  for (int i = 0; i < 2; ++i) {
    int p = i * 512 + tid;
    int m = p >> 3, slot = p & 7;
    int ss = slot ^ (m & 7);
    aSrc[i] = A + (size_t)(row0 + m) * K + ss * 8;
    aOff[i] = p * 8;
    bSrc[i] = B + (size_t)(col0 + m) * K + ss * 8;
    bOff[i] = p * 8;
  }
  const short* bSrc2 = nullptr; int bOff2 = 0;
  if (tid < 256) {
    int p = 1024 + tid;
    int m = p >> 3, slot = p & 7;
    int ss = slot ^ (m & 7);
    bSrc2 = B + (size_t)(col0 + m) * K + ss * 8;
    bOff2 = p * 8;
  }

  const int nkt = K >> 6;   // 45
  for (int kt = 0; kt < nkt; ++kt) {
    __syncthreads();  // previous iter's ds_reads done before overwrite
#pragma unroll
    for (int i = 0; i < 2; ++i) gl_lds16(aSrc[i] + kt * 64, &As[aOff[i]]);
#pragma unroll
    for (int i = 0; i < 2; ++i) gl_lds16(bSrc[i] + kt * 64, &Bs[bOff[i]]);
    if (tid < 256) gl_lds16(bSrc2 + kt * 64, &Bs[bOff2]);
    __syncthreads();  // compiler drains vmcnt(0) before barrier -> LDS ready
#pragma unroll
    for (int kk = 0; kk < 2; ++kk) {
      bf16x8 af[2], bf[5];
#pragma unroll
      for (int mi = 0; mi < 2; ++mi) {
        int r = wm * 32 + mi * 16 + l15;
        int sl = (kk * 4 + lhi) ^ (r & 7);
        af[mi] = *(const bf16x8*)((char*)As + r * 128 + sl * 16);
      }
#pragma unroll
      for (int ni = 0; ni < 5; ++ni) {
        int r = wn * 80 + ni * 16 + l15;
        int sl = (kk * 4 + lhi) ^ (r & 7);
        bf[ni] = *(const bf16x8*)((char*)Bs + r * 128 + sl * 16);
      }
#pragma unroll
      for (int mi = 0; mi < 2; ++mi)
#pragma unroll
        for (int ni = 0; ni < 5; ++ni)
          acc[mi][ni] = __builtin_amdgcn_mfma_f32_16x16x32_bf16(af[mi], bf[ni], acc[mi][ni], 0, 0, 0);
    }
  }

  // epilogue; C layout: col = lane&15, row = (lane>>4)*4 + reg.
#pragma unroll
  for (int mi = 0; mi < 2; ++mi) {
#pragma unroll
    for (int r = 0; r < 4; ++r) {
      int mg = row0 + wm * 32 + mi * 16 + lhi * 4 + r;
#pragma unroll
      for (int ni = 0; ni < 5; ++ni) {
        int ng = col0 + wn * 80 + ni * 16 + l15;
        float v = acc[mi][ni][r];
        v += (ng < NQ) ? biasq[ng] : (ng < NQ + NKVD ? biask[ng - NQ] : biasv[ng - NQ - NKVD]);
        if (ng < NQ + NKVD) {  // RoPE on q and k
          float partner = __shfl_xor(v, 1);
          int d = ng & 63, p = d >> 1;
          float c = cosT[mg * 32 + p], s = sinT[mg * 32 + p];
          v = (d & 1) ? (partner * s + v * c) : (v * c - partner * s);
        }
        short b16 = f2bf(v);
        if (ng < NQ)              qout[(size_t)mg * NQ + ng] = b16;
        else if (ng < NQ + NKVD)  kout[(size_t)mg * NKVD + (ng - NQ)] = b16;
        else                      vout[(size_t)mg * NKVD + (ng - NQ - NKVD)] = b16;
      }
    }
  }
}

// ------------- out-proj GEMM: 128x128 tile, BK=128 (drain-overhead test) -------------
// 512 threads = 8 waves (2x4), wave 64x32 (acc[4][2]). K=4096 -> 32 iters
// (vs 64 at BK=64): halves the per-iteration vmcnt(0)+barrier drains at
// UNCHANGED staged bytes and 2-blocks/CU LDS capacity (64KB). If the GEMM
// residual is drain overhead this gains ~5-8us; if pure staging-service-rate
// (11.2 TB/s) it's null — either way the model is resolved.
// 16-slot XOR swizzle (slot^(m&7)) flips low 3 of 4 slot bits: still a
// closed involution; read rows r, r+8 share a slot -> 2-way (free).
__global__ __launch_bounds__(512) void k_gemm_o(
    const short* __restrict__ A, const short* __restrict__ B,
    const float* __restrict__ bo, float* __restrict__ out) {
  const int K = NQ;
  const int tid = threadIdx.x;
  const int lane = tid & 63, wid = tid >> 6;
  const int wm = wid >> 2, wn = wid & 3;     // 2 x 4 wave grid
  const int l15 = lane & 15, lhi = lane >> 4;
  const int row0 = blockIdx.y * 128, col0 = blockIdx.x * 128;

  __shared__ short As[128 * 128];   // 32KB
  __shared__ short Bs[128 * 128];   // 32KB

  f32x4 acc[4][2];
#pragma unroll
  for (int i = 0; i < 4; ++i)
#pragma unroll
    for (int j = 0; j < 2; ++j) acc[i][j] = (f32x4){0.f, 0.f, 0.f, 0.f};

  // staging: 2048 16B-chunks each for A and B -> 4/thread each.
  // p = i*512+tid; m = p>>4 (16 slots/row), slot = p&15, src ss = slot^(m&7).
  const short* aSrc[4];
  const short* bSrc[4];
  int dOff[4];
#pragma unroll
  for (int i = 0; i < 4; ++i) {
    int p = i * 512 + tid;
    int m = p >> 4, slot = p & 15;
    int ss = slot ^ (m & 7);
    aSrc[i] = A + (size_t)(row0 + m) * K + ss * 8;
    bSrc[i] = B + (size_t)(col0 + m) * K + ss * 8;
    dOff[i] = p * 8;
  }

  const int nkt = K >> 7;   // 32
  for (int kt = 0; kt < nkt; ++kt) {
    __syncthreads();  // previous iter's ds_reads done before overwrite
#pragma unroll
    for (int i = 0; i < 4; ++i) gl_lds16(aSrc[i] + kt * 128, &As[dOff[i]]);
#pragma unroll
    for (int i = 0; i < 4; ++i) gl_lds16(bSrc[i] + kt * 128, &Bs[dOff[i]]);
    __syncthreads();  // compiler drains vmcnt(0) before barrier -> LDS ready
#pragma unroll
    for (int kk = 0; kk < 4; ++kk) {
      bf16x8 af[4], bf[2];
#pragma unroll
      for (int mi = 0; mi < 4; ++mi) {
        int r = wm * 64 + mi * 16 + l15;
        int sl = (kk * 4 + lhi) ^ (r & 7);
        af[mi] = *(const bf16x8*)((char*)As + r * 256 + sl * 16);
      }
#pragma unroll
      for (int ni = 0; ni < 2; ++ni) {
        int r = wn * 32 + ni * 16 + l15;
        int sl = (kk * 4 + lhi) ^ (r & 7);
        bf[ni] = *(const bf16x8*)((char*)Bs + r * 256 + sl * 16);
      }
#pragma unroll
      for (int mi = 0; mi < 4; ++mi)
#pragma unroll
        for (int ni = 0; ni < 2; ++ni)
          acc[mi][ni] = __builtin_amdgcn_mfma_f32_16x16x32_bf16(af[mi], bf[ni], acc[mi][ni], 0, 0, 0);
    }
  }

#pragma unroll
  for (int mi = 0; mi < 4; ++mi) {
#pragma unroll
    for (int r = 0; r < 4; ++r) {
      int mg = row0 + wm * 64 + mi * 16 + lhi * 4 + r;
#pragma unroll
      for (int ni = 0; ni < 2; ++ni) {
        int ng = col0 + wn * 32 + ni * 16 + l15;
        if (ng < HID_DIM) out[(size_t)mg * HID_DIM + ng] = acc[mi][ni][r] + bo[ng];
      }
    }
  }
}

// ---------------- sliding-window attention with sinks ----------------
// grid = 2048 blocks: h = bx&63, qblock = bx>>6 (64 queries). 4 waves x 16 queries.
// Per wave: 9 live 16-key tiles covering keys [q0+wq*16-128, q0+wq*16+15].
// (V staging = R10 version: coalesced global reads + scalar ds writes.
//  R11's b64-packed variant broke global coalescing and regressed; reverted.)
__global__ __launch_bounds__(256) void k_attn(
    const short* __restrict__ qb, const short* __restrict__ kb,
    const short* __restrict__ vb, const float* __restrict__ sinks,
    short* __restrict__ attnb) {
  const int h = blockIdx.x & 63;
  const int q0 = (blockIdx.x >> 6) * 64;
  const int tid = threadIdx.x;
  const int lane = tid & 63, wq = tid >> 6;
  const int l15 = lane & 15, lhi = lane >> 4;
  const int hkv = h >> 3;
  const int kstart = q0 - 128;

  // Vt: [d][key] stride 256, chunk-XOR swizzle: element (d,key) lives at
  // Vt[d*256 + (key ^ ((d&7)<<3))]. Swizzle is closed within 64-key blocks,
  // so the zero region [192,256) maps onto itself.
  __shared__ short Vt[64 * 256];
  __shared__ short Plds[4][16 * 168];     // per-wave P, stride 168 (bank-balanced)

  // zero-fill keys [192,256) for every d row (covers PV reads past live keys)
  {
    int d = tid >> 2;
    int k16 = (tid & 3) * 16;
#pragma unroll
    for (int j = 0; j < 16; j += 4)
      *(short4*)&Vt[d * 256 + 192 + k16 + j] = (short4){0, 0, 0, 0};
  }

  // stage V^T: Vt[d][key] = vb[kstart+key][hkv*64+d], key in [0,192)
  {
    int krow = tid >> 2;            // 0..63
    int dbase = (tid & 3) * 16;
#pragma unroll
    for (int rep = 0; rep < 3; ++rep) {
      int key = rep * 64 + krow;
      int gk = kstart + key;
      int gkc = gk < 0 ? 0 : gk;    // clamped loads are masked later (P=0)
      const short* src = vb + (size_t)gkc * NKVD + hkv * 64 + dbase;
      uint4 v0 = *(const uint4*)(src);
      uint4 v1 = *(const uint4*)(src + 8);
      uint32_t w[8] = {v0.x, v0.y, v0.z, v0.w, v1.x, v1.y, v1.z, v1.w};
#pragma unroll
      for (int i = 0; i < 8; ++i) {
        int d0 = dbase + 2 * i, d1 = dbase + 2 * i + 1;
        Vt[d0 * 256 + (key ^ ((d0 & 7) << 3))] = (short)(w[i] & 0xffffu);
        Vt[d1 * 256 + (key ^ ((d1 & 7) << 3))] = (short)(w[i] >> 16);
      }
    }
  }

  // Q fragments (A-frag: row = lane&15, k = (lane>>4)*8, two 32-wide k halves)
  int qrow = q0 + wq * 16 + l15;
  bf16x8 aq[2];
#pragma unroll
  for (int kk = 0; kk < 2; ++kk)
    aq[kk] = *(const bf16x8*)(qb + (size_t)qrow * NQ + h * 64 + kk * 32 + lhi * 8);

  // S = Q K^T over 9 live tiles
  f32x4 sacc[9];
#pragma unroll
  for (int ni = 0; ni < 9; ++ni) {
    int key = kstart + (wq + ni) * 16 + l15;
    int keyc = key < 0 ? 0 : key;
    const short* kp = kb + (size_t)keyc * NKVD + hkv * 64;
    bf16x8 b0 = *(const bf16x8*)(kp + lhi * 8);
    bf16x8 b1 = *(const bf16x8*)(kp + 32 + lhi * 8);
    f32x4 z = (f32x4){0.f, 0.f, 0.f, 0.f};
    z = __builtin_amdgcn_mfma_f32_16x16x32_bf16(aq[0], b0, z, 0, 0, 0);
    z = __builtin_amdgcn_mfma_f32_16x16x32_bf16(aq[1], b1, z, 0, 0, 0);
    sacc[ni] = z;
  }

  float snk = sinks[h];
  // mask + scale + row max
  float mx[4] = {NEGINF, NEGINF, NEGINF, NEGINF};
#pragma unroll
  for (int ni = 0; ni < 9; ++ni) {
    int j = kstart + (wq + ni) * 16 + l15;
#pragma unroll
    for (int r = 0; r < 4; ++r) {
      int iq = q0 + wq * 16 + lhi * 4 + r;
      float sv = sacc[ni][r] * ATT_SCALE;
      bool valid = (j >= 0) && (j <= iq) && (iq - j < 128);
      sv = valid ? sv : NEGINF;
      sacc[ni][r] = sv;
      mx[r] = fmaxf(mx[r], sv);
    }
  }
#pragma unroll
  for (int r = 0; r < 4; ++r) {
    float m = mx[r];
    m = fmaxf(m, __shfl_xor(m, 1));
    m = fmaxf(m, __shfl_xor(m, 2));
    m = fmaxf(m, __shfl_xor(m, 4));
    m = fmaxf(m, __shfl_xor(m, 8));
    mx[r] = fmaxf(m, snk);
  }
  float sm[4] = {0.f, 0.f, 0.f, 0.f};
#pragma unroll
  for (int ni = 0; ni < 9; ++ni)
#pragma unroll
    for (int r = 0; r < 4; ++r) {
      float p = __expf(sacc[ni][r] - mx[r]);  // exp(-1e30)=0 handles masked
      sacc[ni][r] = p;
      sm[r] += p;
    }
  float inv[4];
#pragma unroll
  for (int r = 0; r < 4; ++r) {
    float s = sm[r];
    s += __shfl_xor(s, 1);
    s += __shfl_xor(s, 2);
    s += __shfl_xor(s, 4);
    s += __shfl_xor(s, 8);
    s += __expf(snk - mx[r]);
    inv[r] = 1.0f / s;
  }

  // P -> LDS (bf16), plus zero-pad tile (cols 144..159) so PV runs 5 K-steps
  short* pw = &Plds[wq][0];
#pragma unroll
  for (int ni = 0; ni < 9; ++ni)
#pragma unroll
    for (int r = 0; r < 4; ++r)
      pw[(lhi * 4 + r) * 168 + ni * 16 + l15] = f2bf(sacc[ni][r]);
#pragma unroll
  for (int r = 0; r < 4; ++r)
    pw[(lhi * 4 + r) * 168 + 144 + l15] = 0;

  __syncthreads();  // Vt staged by all waves; P writes drained

  // O = P V : 16q x 64d per wave, K = 160 (padded)
  f32x4 oacc[4];
#pragma unroll
  for (int nt = 0; nt < 4; ++nt) oacc[nt] = (f32x4){0.f, 0.f, 0.f, 0.f};
  const short* pr = &Plds[wq][0];
#pragma unroll
  for (int ks = 0; ks < 5; ++ks) {
    bf16x8 pf = *(const bf16x8*)(pr + l15 * 168 + ks * 32 + lhi * 8);
#pragma unroll
    for (int nt = 0; nt < 4; ++nt) {
      int d = nt * 16 + l15;
      int keyidx = wq * 16 + ks * 32 + lhi * 8;           // 8-aligned
      bf16x8 vf = *(const bf16x8*)(&Vt[d * 256 + (keyidx ^ ((d & 7) << 3))]);
      oacc[nt] = __builtin_amdgcn_mfma_f32_16x16x32_bf16(pf, vf, oacc[nt], 0, 0, 0);
    }
  }

#pragma unroll
  for (int nt = 0; nt < 4; ++nt)
#pragma unroll
    for (int r = 0; r < 4; ++r) {
      int iq = q0 + wq * 16 + lhi * 4 + r;
      int d = nt * 16 + l15;
      attnb[(size_t)iq * NQ + h * 64 + d] = f2bf(oacc[nt][r] * inv[r]);
    }
}

// ---------------- launch ----------------
extern "C" void kernel_launch(void* const* d_in, const int* in_sizes, int n_in,
                              void* d_out, int out_size, void* d_ws, size_t ws_size,
                              hipStream_t stream) {
  const float* x     = (const float*)d_in[0];
  const float* cosT  = (const float*)d_in[1];
  const float* sinT  = (const float*)d_in[2];
  const float* Wq    = (const float*)d_in[3];
  const float* bq    = (const float*)d_in[4];
  const float* Wk    = (const float*)d_in[5];
  const float* bk    = (const float*)d_in[6];
  const float* Wv    = (const float*)d_in[7];
  const float* bv    = (const float*)d_in[8];
  const float* Wo    = (const float*)d_in[9];
  const float* bo    = (const float*)d_in[10];
  const float* sinks = (const float*)d_in[11];
  float* out = (float*)d_out;

  // workspace layout (bf16 shorts), total ~103.2 MB
  short* xb    = (short*)d_ws;
  short* wqkvb = xb + (size_t)S_LEN * HID_DIM;                 // [5120][2880]
  short* wob   = wqkvb + (size_t)NQKV * HID_DIM;               // [2944][4096]
  short* qbuf  = wob + (size_t)WOPAD * NQ;                     // [2048][4096]
  short* kbuf  = qbuf + (size_t)S_LEN * NQ;                    // [2048][512]
  short* vbuf  = kbuf + (size_t)S_LEN * NKVD;                  // [2048][512]
  short* attnb = vbuf + (size_t)S_LEN * NKVD;                  // [2048][4096]

  k_prep<<<31936, 256, 0, stream>>>(x, xb, Wq, Wk, Wv, Wo, wqkvb, wob);

  k_gemm_qkv<<<dim3(NQKV / 160, S_LEN / 128), 512, 0, stream>>>(
      xb, wqkvb, bq, bk, bv, cosT, sinT, qbuf, kbuf, vbuf);

  k_attn<<<(S_LEN / 64) * NHEAD, 256, 0, stream>>>(qbuf, kbuf, vbuf, sinks, attnb);

  k_gemm_o<<<dim3(WOPAD / 128, S_LEN / 128), 512, 0, stream>>>(
      attnb, wob, bo, out);
}